// Round 1
// baseline (358.574 us; speedup 1.0000x reference)
//
#include <hip/hip_runtime.h>
#include <math.h>

// BertBidafAttention: B=16, CL=512, QL=64, H=768
// cp = c @ W^T + b                    [B*CL, H]
// s  = cp @ q^T (per batch)           [B, CL, QL]
// s1 = softmax_q(mask_q(s))           [B, CL, QL]
// s2 = softmax_c(mask_c(s))           [B, CL, QL]
// t  = s2^T @ c (per batch)           [B, QL, H]   <-- algebraic contraction of ss@c
// a  = s1 @ q ; bvec = s1 @ t
// out = [c, a, c*a, c*bvec]           [B, CL, 4H]

#define B_  16
#define CL_ 512
#define QL_ 64
#define H_  768
#define M_  (B_ * CL_)   // 8192

// ---------------- K1: cp = c @ W^T + bias  (NT GEMM, f32) ----------------
// 64x64 tile, K-tile 16, 256 threads, 4x4 microtile/thread.
__global__ __launch_bounds__(256) void k_gemm_cp(
    const float* __restrict__ A,    // [M_, H_]
    const float* __restrict__ W,    // [H_, H_] (row n is W[n, :])
    const float* __restrict__ bias, // [H_]
    float* __restrict__ C)          // [M_, H_]
{
    __shared__ float As[16][68];  // k-major, padded (row = 272B, 16B-aligned)
    __shared__ float Bs[16][68];
    const int tid = threadIdx.x;
    const int tx = tid & 15, ty = tid >> 4;
    const int m0 = blockIdx.x * 64, n0 = blockIdx.y * 64;
    const int lr = tid >> 2;          // 0..63 tile row
    const int lk = (tid & 3) << 2;    // 0,4,8,12 k offset
    const float* Ap = A + (size_t)(m0 + lr) * H_ + lk;
    const float* Wp = W + (size_t)(n0 + lr) * H_ + lk;
    float acc[4][4] = {};
    for (int k0 = 0; k0 < H_; k0 += 16) {
        float4 av = *(const float4*)(Ap + k0);
        float4 wv = *(const float4*)(Wp + k0);
        __syncthreads();
        As[lk+0][lr] = av.x; As[lk+1][lr] = av.y; As[lk+2][lr] = av.z; As[lk+3][lr] = av.w;
        Bs[lk+0][lr] = wv.x; Bs[lk+1][lr] = wv.y; Bs[lk+2][lr] = wv.z; Bs[lk+3][lr] = wv.w;
        __syncthreads();
#pragma unroll
        for (int k = 0; k < 16; ++k) {
            float4 a4 = *(const float4*)&As[k][ty * 4];
            float4 b4 = *(const float4*)&Bs[k][tx * 4];
            float ar[4] = {a4.x, a4.y, a4.z, a4.w};
            float br[4] = {b4.x, b4.y, b4.z, b4.w};
#pragma unroll
            for (int i = 0; i < 4; ++i)
#pragma unroll
                for (int j = 0; j < 4; ++j)
                    acc[i][j] = fmaf(ar[i], br[j], acc[i][j]);
        }
    }
    float4 bb = *(const float4*)&bias[n0 + tx * 4];
#pragma unroll
    for (int i = 0; i < 4; ++i) {
        float4 o;
        o.x = acc[i][0] + bb.x; o.y = acc[i][1] + bb.y;
        o.z = acc[i][2] + bb.z; o.w = acc[i][3] + bb.w;
        *(float4*)&C[(size_t)(m0 + ty * 4 + i) * H_ + n0 + tx * 4] = o;
    }
}

// ---------------- K2: s = cp @ q^T per batch ----------------
// M=8192 rows (batch = row/512), N=64 (all QL), K=768.
__global__ __launch_bounds__(256) void k_gemm_s(
    const float* __restrict__ cp,  // [M_, H_]
    const float* __restrict__ q,   // [B_, QL_, H_]
    float* __restrict__ s)         // [M_, QL_]
{
    __shared__ float As[16][68];
    __shared__ float Bs[16][68];
    const int tid = threadIdx.x;
    const int tx = tid & 15, ty = tid >> 4;
    const int m0 = blockIdx.x * 64;
    const int batch = m0 >> 9;  // CL_=512
    const int lr = tid >> 2;
    const int lk = (tid & 3) << 2;
    const float* Ap = cp + (size_t)(m0 + lr) * H_ + lk;
    const float* Qp = q + (size_t)(batch * QL_ + lr) * H_ + lk;
    float acc[4][4] = {};
    for (int k0 = 0; k0 < H_; k0 += 16) {
        float4 av = *(const float4*)(Ap + k0);
        float4 qv = *(const float4*)(Qp + k0);
        __syncthreads();
        As[lk+0][lr] = av.x; As[lk+1][lr] = av.y; As[lk+2][lr] = av.z; As[lk+3][lr] = av.w;
        Bs[lk+0][lr] = qv.x; Bs[lk+1][lr] = qv.y; Bs[lk+2][lr] = qv.z; Bs[lk+3][lr] = qv.w;
        __syncthreads();
#pragma unroll
        for (int k = 0; k < 16; ++k) {
            float4 a4 = *(const float4*)&As[k][ty * 4];
            float4 b4 = *(const float4*)&Bs[k][tx * 4];
            float ar[4] = {a4.x, a4.y, a4.z, a4.w};
            float br[4] = {b4.x, b4.y, b4.z, b4.w};
#pragma unroll
            for (int i = 0; i < 4; ++i)
#pragma unroll
                for (int j = 0; j < 4; ++j)
                    acc[i][j] = fmaf(ar[i], br[j], acc[i][j]);
        }
    }
#pragma unroll
    for (int i = 0; i < 4; ++i) {
        float4 o = make_float4(acc[i][0], acc[i][1], acc[i][2], acc[i][3]);
        *(float4*)&s[(size_t)(m0 + ty * 4 + i) * QL_ + tx * 4] = o;
    }
}

// ---------------- K3: s1 = row softmax over q (one wave per row) ----------------
__global__ __launch_bounds__(256) void k_softmax_rows(
    const float* __restrict__ s, const int* __restrict__ q_mask,
    float* __restrict__ s1)
{
    const int row  = blockIdx.x * 4 + (threadIdx.x >> 6);
    const int lane = threadIdx.x & 63;
    const int batch = row >> 9;
    float v = s[(size_t)row * QL_ + lane];
    float x = q_mask[batch * QL_ + lane] ? v : -1e30f;
    float mx = x;
#pragma unroll
    for (int off = 32; off; off >>= 1) mx = fmaxf(mx, __shfl_xor(mx, off));
    float e = __expf(x - mx);
    float sm = e;
#pragma unroll
    for (int off = 32; off; off >>= 1) sm += __shfl_xor(sm, off);
    s1[(size_t)row * QL_ + lane] = e / sm;
}

// ---------------- K4: s2 = column softmax over c (one block per (b,q)) ----------------
__global__ __launch_bounds__(256) void k_softmax_cols(
    const float* __restrict__ s, const int* __restrict__ c_mask,
    float* __restrict__ s2)
{
    __shared__ float red[4];
    const int b = blockIdx.x >> 6, qi = blockIdx.x & 63;
    const int tid = threadIdx.x;
    const float* sb = s + (size_t)b * CL_ * QL_ + qi;
    const int* cm = c_mask + b * CL_;
    const int cA = tid, cB = tid + 256;
    float x0 = cm[cA] ? sb[(size_t)cA * QL_] : -1e30f;
    float x1 = cm[cB] ? sb[(size_t)cB * QL_] : -1e30f;
    float m = fmaxf(x0, x1);
#pragma unroll
    for (int off = 32; off; off >>= 1) m = fmaxf(m, __shfl_xor(m, off));
    if ((tid & 63) == 0) red[tid >> 6] = m;
    __syncthreads();
    m = fmaxf(fmaxf(red[0], red[1]), fmaxf(red[2], red[3]));
    __syncthreads();
    float e0 = __expf(x0 - m), e1 = __expf(x1 - m);
    float sm = e0 + e1;
#pragma unroll
    for (int off = 32; off; off >>= 1) sm += __shfl_xor(sm, off);
    if ((tid & 63) == 0) red[tid >> 6] = sm;
    __syncthreads();
    sm = red[0] + red[1] + red[2] + red[3];
    float inv = 1.0f / sm;
    s2[((size_t)b * CL_ + cA) * QL_ + qi] = e0 * inv;
    s2[((size_t)b * CL_ + cB) * QL_ + qi] = e1 * inv;
}

// ---------------- K5: t = s2^T @ c per batch  [B_, QL_, H_] ----------------
// Tile: 64 q x 64 h, K over d (512). Both operands are k(d)-major in memory.
__global__ __launch_bounds__(256) void k_gemm_t(
    const float* __restrict__ s2,  // [B_, CL_, QL_]
    const float* __restrict__ c,   // [B_, CL_, H_]
    float* __restrict__ t)         // [B_, QL_, H_]
{
    __shared__ float Ss[16][68];  // [d][q]
    __shared__ float Cs[16][68];  // [d][h]
    const int tid = threadIdx.x;
    const int tx = tid & 15, ty = tid >> 4;
    const int b = blockIdx.y, h0 = blockIdx.x * 64;
    const int ld = tid >> 4;          // 0..15 d row
    const int lo = (tid & 15) << 2;   // col offset
    float acc[4][4] = {};
    for (int d0 = 0; d0 < CL_; d0 += 16) {
        float4 sv = *(const float4*)&s2[((size_t)b * CL_ + d0 + ld) * QL_ + lo];
        float4 cv = *(const float4*)&c[((size_t)b * CL_ + d0 + ld) * H_ + h0 + lo];
        __syncthreads();
        *(float4*)&Ss[ld][lo] = sv;
        *(float4*)&Cs[ld][lo] = cv;
        __syncthreads();
#pragma unroll
        for (int d = 0; d < 16; ++d) {
            float4 a4 = *(const float4*)&Ss[d][ty * 4];
            float4 b4 = *(const float4*)&Cs[d][tx * 4];
            float ar[4] = {a4.x, a4.y, a4.z, a4.w};
            float br[4] = {b4.x, b4.y, b4.z, b4.w};
#pragma unroll
            for (int i = 0; i < 4; ++i)
#pragma unroll
                for (int j = 0; j < 4; ++j)
                    acc[i][j] = fmaf(ar[i], br[j], acc[i][j]);
        }
    }
#pragma unroll
    for (int i = 0; i < 4; ++i) {
        float4 o = make_float4(acc[i][0], acc[i][1], acc[i][2], acc[i][3]);
        *(float4*)&t[((size_t)b * QL_ + ty * 4 + i) * H_ + h0 + tx * 4] = o;
    }
}

// ---------------- K6: finalize — a = s1@q, bvec = s1@t, write 4 segments ----------------
// K=64 (single pass). Tile: 64 c x 64 h per block.
__global__ __launch_bounds__(256) void k_finalize(
    const float* __restrict__ s1,  // [B_, CL_, QL_]
    const float* __restrict__ q,   // [B_, QL_, H_]
    const float* __restrict__ t,   // [B_, QL_, H_]
    const float* __restrict__ c,   // [B_, CL_, H_]
    float* __restrict__ out)       // [B_, CL_, 4*H_]
{
    __shared__ float S1s[64][68];  // [q][c]  (transposed on load)
    __shared__ float Qs[64][68];   // [q][h]
    __shared__ float Ts[64][68];   // [q][h]
    const int tid = threadIdx.x;
    const int tx = tid & 15, ty = tid >> 4;
    const int b = blockIdx.z, c0 = blockIdx.y * 64, h0 = blockIdx.x * 64;
    {
        const int rbase = tid >> 4;        // 0..15
        const int o4 = (tid & 15) << 2;    // 0..60
#pragma unroll
        for (int rr = 0; rr < 4; ++rr) {
            int r = rr * 16 + rbase;
            float4 v = *(const float4*)&s1[((size_t)b * CL_ + c0 + r) * QL_ + o4];
            S1s[o4 + 0][r] = v.x; S1s[o4 + 1][r] = v.y;
            S1s[o4 + 2][r] = v.z; S1s[o4 + 3][r] = v.w;
            *(float4*)&Qs[r][o4] = *(const float4*)&q[((size_t)b * QL_ + r) * H_ + h0 + o4];
            *(float4*)&Ts[r][o4] = *(const float4*)&t[((size_t)b * QL_ + r) * H_ + h0 + o4];
        }
    }
    __syncthreads();
    float aa[4][4] = {}, bb[4][4] = {};
#pragma unroll
    for (int k = 0; k < 64; ++k) {
        float4 s4 = *(const float4*)&S1s[k][ty * 4];
        float4 q4 = *(const float4*)&Qs[k][tx * 4];
        float4 t4 = *(const float4*)&Ts[k][tx * 4];
        float sr[4] = {s4.x, s4.y, s4.z, s4.w};
        float qr[4] = {q4.x, q4.y, q4.z, q4.w};
        float tr[4] = {t4.x, t4.y, t4.z, t4.w};
#pragma unroll
        for (int i = 0; i < 4; ++i)
#pragma unroll
            for (int j = 0; j < 4; ++j) {
                aa[i][j] = fmaf(sr[i], qr[j], aa[i][j]);
                bb[i][j] = fmaf(sr[i], tr[j], bb[i][j]);
            }
    }
#pragma unroll
    for (int i = 0; i < 4; ++i) {
        const int crow = c0 + ty * 4 + i;
        const float4 cv = *(const float4*)&c[((size_t)b * CL_ + crow) * H_ + h0 + tx * 4];
        float* ob = out + ((size_t)b * CL_ + crow) * (4 * H_);
        const int hh = h0 + tx * 4;
        float4 av  = make_float4(aa[i][0], aa[i][1], aa[i][2], aa[i][3]);
        float4 bv  = make_float4(bb[i][0], bb[i][1], bb[i][2], bb[i][3]);
        float4 cav = make_float4(cv.x * av.x, cv.y * av.y, cv.z * av.z, cv.w * av.w);
        float4 cbv = make_float4(cv.x * bv.x, cv.y * bv.y, cv.z * bv.z, cv.w * bv.w);
        *(float4*)&ob[hh]           = cv;
        *(float4*)&ob[H_ + hh]      = av;
        *(float4*)&ob[2 * H_ + hh]  = cav;
        *(float4*)&ob[3 * H_ + hh]  = cbv;
    }
}

extern "C" void kernel_launch(void* const* d_in, const int* in_sizes, int n_in,
                              void* d_out, int out_size, void* d_ws, size_t ws_size,
                              hipStream_t stream) {
    const float* c      = (const float*)d_in[0];
    const float* q      = (const float*)d_in[1];
    const int*   c_mask = (const int*)d_in[2];
    const int*   q_mask = (const int*)d_in[3];
    const float* W      = (const float*)d_in[4];
    const float* bias   = (const float*)d_in[5];
    float* out = (float*)d_out;

    // workspace layout (floats): cp[8192*768] s[8192*64] s1[8192*64] s2[8192*64] t[16*64*768]
    float* ws = (float*)d_ws;
    float* cp = ws;                       // 6291456
    float* s  = cp + (size_t)M_ * H_;     // 524288
    float* s1 = s  + (size_t)M_ * QL_;    // 524288
    float* s2 = s1 + (size_t)M_ * QL_;    // 524288
    float* t  = s2 + (size_t)M_ * QL_;    // 786432

    dim3 blk(256);
    k_gemm_cp     <<<dim3(M_ / 64, H_ / 64), blk, 0, stream>>>(c, W, bias, cp);
    k_gemm_s      <<<dim3(M_ / 64),          blk, 0, stream>>>(cp, q, s);
    k_softmax_rows<<<dim3(M_ / 4),           blk, 0, stream>>>(s, q_mask, s1);
    k_softmax_cols<<<dim3(B_ * QL_),         blk, 0, stream>>>(s, c_mask, s2);
    k_gemm_t      <<<dim3(H_ / 64, B_),      blk, 0, stream>>>(s2, c, t);
    k_finalize    <<<dim3(H_ / 64, CL_ / 64, B_), blk, 0, stream>>>(s1, q, t, c, out);
}

// Round 2
// 257.691 us; speedup vs baseline: 1.3915x; 1.3915x over previous
//
#include <hip/hip_runtime.h>
#include <math.h>

// BertBidafAttention: B=16, CL=512, QL=64, H=768
// cp = c @ W^T + b     (split-bf16 MFMA)  -> cph/cpl bf16
// s  = cp @ q^T        (split-bf16 MFMA)  -> f32
// s1 = softmax_q(s), s2 = softmax_c(s)
// t  = s2^T @ c ;  a = s1@q ; bvec = s1@t
// out = [c, a, c*a, c*bvec]

#define B_  16
#define CL_ 512
#define QL_ 64
#define H_  768
#define M_  (B_ * CL_)   // 8192

typedef __attribute__((ext_vector_type(8))) short s8v;   // 8 bf16 (4 VGPR)
typedef __attribute__((ext_vector_type(4))) float f4v;   // MFMA acc

// ---- bf16 split helpers (RNE) ----
__device__ __forceinline__ unsigned short bf16_rne(float x) {
    unsigned int u = __float_as_uint(x);
    u += 0x7fffu + ((u >> 16) & 1u);
    return (unsigned short)(u >> 16);
}
__device__ __forceinline__ float bf16_f(unsigned short h) {
    return __uint_as_float((unsigned int)h << 16);
}
__device__ __forceinline__ void split2(float x, unsigned short& h, unsigned short& l) {
    h = bf16_rne(x);
    l = bf16_rne(x - bf16_f(h));
}

// ---------------- K0: elementwise f32 -> (hi, lo) bf16 split ----------------
__global__ __launch_bounds__(256) void k_split(
    const float* __restrict__ x, unsigned short* __restrict__ h,
    unsigned short* __restrict__ l, int n4)
{
    int i = blockIdx.x * 256 + threadIdx.x;
    if (i >= n4) return;
    float4 v = ((const float4*)x)[i];
    ushort4 hh, ll;
    split2(v.x, hh.x, ll.x); split2(v.y, hh.y, ll.y);
    split2(v.z, hh.z, ll.z); split2(v.w, hh.w, ll.w);
    ((ushort4*)h)[i] = hh;
    ((ushort4*)l)[i] = ll;
}

// ---------------- K1: cp = c @ W^T + bias (split-bf16 MFMA) ----------------
// 128x128 block tile, 4 waves (2x2), each wave 64x64 = 4x4 16x16 tiles.
// A (c) converted f32->split inline; B (W) pre-split. Output: split bf16.
__global__ __launch_bounds__(256) void k_gemm_cp(
    const float* __restrict__ A,                 // c [M_, H_] f32
    const unsigned short* __restrict__ Wh,       // [H_, H_] bf16 bits
    const unsigned short* __restrict__ Wl,
    const float* __restrict__ bias,              // [H_]
    unsigned short* __restrict__ Ch,             // cp hi [M_, H_]
    unsigned short* __restrict__ Cl)             // cp lo
{
    __shared__ unsigned short Ah[128][40], Al[128][40];
    __shared__ unsigned short Bh[128][40], Bl[128][40];
    const int tid = threadIdx.x;
    const int m0 = blockIdx.x * 128, n0 = blockIdx.y * 128;
    const int wv = tid >> 6, lane = tid & 63;
    const int wm = (wv & 1) * 64, wn = (wv >> 1) * 64;
    const int fm = lane & 15, quad = lane >> 4;
    const f4v z = {0.f, 0.f, 0.f, 0.f};
    f4v acc[4][4];
#pragma unroll
    for (int i = 0; i < 4; ++i)
#pragma unroll
        for (int j = 0; j < 4; ++j) acc[i][j] = z;

    const int arow = tid >> 3;          // 0..31 (+i*32)
    const int acol = (tid & 7) * 4;     // 0..28
    const int brow = tid >> 2;          // 0..63 (+64)
    const int bchunk = (tid & 3) * 8;   // shorts: 0,8,16,24

    for (int k0 = 0; k0 < H_; k0 += 32) {
        float4 av[4];
#pragma unroll
        for (int i = 0; i < 4; ++i)
            av[i] = *(const float4*)&A[(size_t)(m0 + i * 32 + arow) * H_ + k0 + acol];
        s8v wh0 = *(const s8v*)&Wh[(size_t)(n0 + brow) * H_ + k0 + bchunk];
        s8v wh1 = *(const s8v*)&Wh[(size_t)(n0 + 64 + brow) * H_ + k0 + bchunk];
        s8v wl0 = *(const s8v*)&Wl[(size_t)(n0 + brow) * H_ + k0 + bchunk];
        s8v wl1 = *(const s8v*)&Wl[(size_t)(n0 + 64 + brow) * H_ + k0 + bchunk];
        __syncthreads();
#pragma unroll
        for (int i = 0; i < 4; ++i) {
            float xs[4] = {av[i].x, av[i].y, av[i].z, av[i].w};
            ushort4 hh, ll;
            split2(xs[0], hh.x, ll.x); split2(xs[1], hh.y, ll.y);
            split2(xs[2], hh.z, ll.z); split2(xs[3], hh.w, ll.w);
            *(ushort4*)&Ah[i * 32 + arow][acol] = hh;
            *(ushort4*)&Al[i * 32 + arow][acol] = ll;
        }
        *(s8v*)&Bh[brow][bchunk] = wh0;
        *(s8v*)&Bh[64 + brow][bchunk] = wh1;
        *(s8v*)&Bl[brow][bchunk] = wl0;
        *(s8v*)&Bl[64 + brow][bchunk] = wl1;
        __syncthreads();

        s8v fah[4], fal[4], fbh[4], fbl[4];
#pragma unroll
        for (int t = 0; t < 4; ++t) {
            fah[t] = *(const s8v*)&Ah[wm + t * 16 + fm][quad * 8];
            fal[t] = *(const s8v*)&Al[wm + t * 16 + fm][quad * 8];
            fbh[t] = *(const s8v*)&Bh[wn + t * 16 + fm][quad * 8];
            fbl[t] = *(const s8v*)&Bl[wn + t * 16 + fm][quad * 8];
        }
#pragma unroll
        for (int tm = 0; tm < 4; ++tm)
#pragma unroll
            for (int tn = 0; tn < 4; ++tn) {
                acc[tm][tn] = __builtin_amdgcn_mfma_f32_16x16x32_bf16(fah[tm], fbh[tn], acc[tm][tn], 0, 0, 0);
                acc[tm][tn] = __builtin_amdgcn_mfma_f32_16x16x32_bf16(fah[tm], fbl[tn], acc[tm][tn], 0, 0, 0);
                acc[tm][tn] = __builtin_amdgcn_mfma_f32_16x16x32_bf16(fal[tm], fbh[tn], acc[tm][tn], 0, 0, 0);
            }
    }
    // epilogue: D row=(quad*4+r), col=fm within tile
#pragma unroll
    for (int tm = 0; tm < 4; ++tm)
#pragma unroll
        for (int tn = 0; tn < 4; ++tn) {
            const int col = n0 + wn + tn * 16 + fm;
            const float bb = bias[col];
#pragma unroll
            for (int r = 0; r < 4; ++r) {
                const int row = m0 + wm + tm * 16 + quad * 4 + r;
                float v = acc[tm][tn][r] + bb;
                unsigned short h, l;
                split2(v, h, l);
                size_t o = (size_t)row * H_ + col;
                Ch[o] = h; Cl[o] = l;
            }
        }
}

// ---------------- K2: s = cp @ q^T per batch (split-bf16 MFMA) ----------------
// 128x64 block tile, grid 64. 4 waves stacked along M (32 rows each).
__global__ __launch_bounds__(256) void k_gemm_s(
    const unsigned short* __restrict__ Ch, const unsigned short* __restrict__ Cl,  // [M_, H_]
    const unsigned short* __restrict__ Qh, const unsigned short* __restrict__ Ql,  // [B_*QL_, H_]
    float* __restrict__ s)                                                          // [M_, QL_]
{
    __shared__ unsigned short Ah[128][40], Al[128][40];
    __shared__ unsigned short Bh[64][40], Bl[64][40];
    const int tid = threadIdx.x;
    const int m0 = blockIdx.x * 128;
    const int batch = m0 >> 9;
    const int wv = tid >> 6, lane = tid & 63;
    const int fm = lane & 15, quad = lane >> 4;
    const f4v z = {0.f, 0.f, 0.f, 0.f};
    f4v acc[2][4];
#pragma unroll
    for (int i = 0; i < 2; ++i)
#pragma unroll
        for (int j = 0; j < 4; ++j) acc[i][j] = z;

    const int arow0 = tid >> 1;                 // slot t: rows via slot>>2? use two slots
    (void)arow0;
    const int sl0 = tid, sl1 = tid + 256;       // 512 chunk-slots for A (128 rows x 4 chunks)
    const int ar0 = sl0 >> 2, ac0 = (sl0 & 3) * 8;
    const int ar1 = sl1 >> 2, ac1 = (sl1 & 3) * 8;
    const int brow = tid >> 2, bchunk = (tid & 3) * 8;  // 256 slots for B (64 x 4)

    for (int k0 = 0; k0 < H_; k0 += 32) {
        s8v a0h = *(const s8v*)&Ch[(size_t)(m0 + ar0) * H_ + k0 + ac0];
        s8v a1h = *(const s8v*)&Ch[(size_t)(m0 + ar1) * H_ + k0 + ac1];
        s8v a0l = *(const s8v*)&Cl[(size_t)(m0 + ar0) * H_ + k0 + ac0];
        s8v a1l = *(const s8v*)&Cl[(size_t)(m0 + ar1) * H_ + k0 + ac1];
        s8v b0h = *(const s8v*)&Qh[(size_t)(batch * QL_ + brow) * H_ + k0 + bchunk];
        s8v b0l = *(const s8v*)&Ql[(size_t)(batch * QL_ + brow) * H_ + k0 + bchunk];
        __syncthreads();
        *(s8v*)&Ah[ar0][ac0] = a0h; *(s8v*)&Ah[ar1][ac1] = a1h;
        *(s8v*)&Al[ar0][ac0] = a0l; *(s8v*)&Al[ar1][ac1] = a1l;
        *(s8v*)&Bh[brow][bchunk] = b0h;
        *(s8v*)&Bl[brow][bchunk] = b0l;
        __syncthreads();

        s8v fah[2], fal[2], fbh[4], fbl[4];
#pragma unroll
        for (int t = 0; t < 2; ++t) {
            fah[t] = *(const s8v*)&Ah[wv * 32 + t * 16 + fm][quad * 8];
            fal[t] = *(const s8v*)&Al[wv * 32 + t * 16 + fm][quad * 8];
        }
#pragma unroll
        for (int t = 0; t < 4; ++t) {
            fbh[t] = *(const s8v*)&Bh[t * 16 + fm][quad * 8];
            fbl[t] = *(const s8v*)&Bl[t * 16 + fm][quad * 8];
        }
#pragma unroll
        for (int tm = 0; tm < 2; ++tm)
#pragma unroll
            for (int tn = 0; tn < 4; ++tn) {
                acc[tm][tn] = __builtin_amdgcn_mfma_f32_16x16x32_bf16(fah[tm], fbh[tn], acc[tm][tn], 0, 0, 0);
                acc[tm][tn] = __builtin_amdgcn_mfma_f32_16x16x32_bf16(fah[tm], fbl[tn], acc[tm][tn], 0, 0, 0);
                acc[tm][tn] = __builtin_amdgcn_mfma_f32_16x16x32_bf16(fal[tm], fbh[tn], acc[tm][tn], 0, 0, 0);
            }
    }
#pragma unroll
    for (int tm = 0; tm < 2; ++tm)
#pragma unroll
        for (int tn = 0; tn < 4; ++tn) {
            const int col = tn * 16 + fm;
#pragma unroll
            for (int r = 0; r < 4; ++r) {
                const int row = m0 + wv * 32 + tm * 16 + quad * 4 + r;
                s[(size_t)row * QL_ + col] = acc[tm][tn][r];
            }
        }
}

// ---------------- K3: s1 = row softmax over q (one wave per row) ----------------
__global__ __launch_bounds__(256) void k_softmax_rows(
    const float* __restrict__ s, const int* __restrict__ q_mask,
    float* __restrict__ s1)
{
    const int row  = blockIdx.x * 4 + (threadIdx.x >> 6);
    const int lane = threadIdx.x & 63;
    const int batch = row >> 9;
    float v = s[(size_t)row * QL_ + lane];
    float x = q_mask[batch * QL_ + lane] ? v : -1e30f;
    float mx = x;
#pragma unroll
    for (int off = 32; off; off >>= 1) mx = fmaxf(mx, __shfl_xor(mx, off));
    float e = __expf(x - mx);
    float sm = e;
#pragma unroll
    for (int off = 32; off; off >>= 1) sm += __shfl_xor(sm, off);
    s1[(size_t)row * QL_ + lane] = e / sm;
}

// ---------------- K4: s2 = column softmax over c (one block per (b,q)) ----------------
__global__ __launch_bounds__(256) void k_softmax_cols(
    const float* __restrict__ s, const int* __restrict__ c_mask,
    float* __restrict__ s2)
{
    __shared__ float red[4];
    const int b = blockIdx.x >> 6, qi = blockIdx.x & 63;
    const int tid = threadIdx.x;
    const float* sb = s + (size_t)b * CL_ * QL_ + qi;
    const int* cm = c_mask + b * CL_;
    const int cA = tid, cB = tid + 256;
    float x0 = cm[cA] ? sb[(size_t)cA * QL_] : -1e30f;
    float x1 = cm[cB] ? sb[(size_t)cB * QL_] : -1e30f;
    float m = fmaxf(x0, x1);
#pragma unroll
    for (int off = 32; off; off >>= 1) m = fmaxf(m, __shfl_xor(m, off));
    if ((tid & 63) == 0) red[tid >> 6] = m;
    __syncthreads();
    m = fmaxf(fmaxf(red[0], red[1]), fmaxf(red[2], red[3]));
    __syncthreads();
    float e0 = __expf(x0 - m), e1 = __expf(x1 - m);
    float sm = e0 + e1;
#pragma unroll
    for (int off = 32; off; off >>= 1) sm += __shfl_xor(sm, off);
    if ((tid & 63) == 0) red[tid >> 6] = sm;
    __syncthreads();
    sm = red[0] + red[1] + red[2] + red[3];
    float inv = 1.0f / sm;
    s2[((size_t)b * CL_ + cA) * QL_ + qi] = e0 * inv;
    s2[((size_t)b * CL_ + cB) * QL_ + qi] = e1 * inv;
}

// ---------------- K5: t = s2^T @ c per batch  [B_, QL_, H_] (f32) ----------------
__global__ __launch_bounds__(256) void k_gemm_t(
    const float* __restrict__ s2, const float* __restrict__ c,
    float* __restrict__ t)
{
    __shared__ float Ss[16][68];
    __shared__ float Cs[16][68];
    const int tid = threadIdx.x;
    const int tx = tid & 15, ty = tid >> 4;
    const int b = blockIdx.y, h0 = blockIdx.x * 64;
    const int ld = tid >> 4;
    const int lo = (tid & 15) << 2;
    float acc[4][4] = {};
    for (int d0 = 0; d0 < CL_; d0 += 16) {
        float4 sv = *(const float4*)&s2[((size_t)b * CL_ + d0 + ld) * QL_ + lo];
        float4 cv = *(const float4*)&c[((size_t)b * CL_ + d0 + ld) * H_ + h0 + lo];
        __syncthreads();
        *(float4*)&Ss[ld][lo] = sv;
        *(float4*)&Cs[ld][lo] = cv;
        __syncthreads();
#pragma unroll
        for (int d = 0; d < 16; ++d) {
            float4 a4 = *(const float4*)&Ss[d][ty * 4];
            float4 b4 = *(const float4*)&Cs[d][tx * 4];
            float ar[4] = {a4.x, a4.y, a4.z, a4.w};
            float br[4] = {b4.x, b4.y, b4.z, b4.w};
#pragma unroll
            for (int i = 0; i < 4; ++i)
#pragma unroll
                for (int j = 0; j < 4; ++j)
                    acc[i][j] = fmaf(ar[i], br[j], acc[i][j]);
        }
    }
#pragma unroll
    for (int i = 0; i < 4; ++i) {
        float4 o = make_float4(acc[i][0], acc[i][1], acc[i][2], acc[i][3]);
        *(float4*)&t[((size_t)b * QL_ + ty * 4 + i) * H_ + h0 + tx * 4] = o;
    }
}

// ---------------- K6: finalize — a = s1@q, bvec = s1@t, write 4 segments ----------------
__global__ __launch_bounds__(256) void k_finalize(
    const float* __restrict__ s1, const float* __restrict__ q,
    const float* __restrict__ t, const float* __restrict__ c,
    float* __restrict__ out)
{
    __shared__ float S1s[64][68];
    __shared__ float Qs[64][68];
    __shared__ float Ts[64][68];
    const int tid = threadIdx.x;
    const int tx = tid & 15, ty = tid >> 4;
    const int b = blockIdx.z, c0 = blockIdx.y * 64, h0 = blockIdx.x * 64;
    {
        const int rbase = tid >> 4;
        const int o4 = (tid & 15) << 2;
#pragma unroll
        for (int rr = 0; rr < 4; ++rr) {
            int r = rr * 16 + rbase;
            float4 v = *(const float4*)&s1[((size_t)b * CL_ + c0 + r) * QL_ + o4];
            S1s[o4 + 0][r] = v.x; S1s[o4 + 1][r] = v.y;
            S1s[o4 + 2][r] = v.z; S1s[o4 + 3][r] = v.w;
            *(float4*)&Qs[r][o4] = *(const float4*)&q[((size_t)b * QL_ + r) * H_ + h0 + o4];
            *(float4*)&Ts[r][o4] = *(const float4*)&t[((size_t)b * QL_ + r) * H_ + h0 + o4];
        }
    }
    __syncthreads();
    float aa[4][4] = {}, bb[4][4] = {};
#pragma unroll
    for (int k = 0; k < 64; ++k) {
        float4 s4 = *(const float4*)&S1s[k][ty * 4];
        float4 q4 = *(const float4*)&Qs[k][tx * 4];
        float4 t4 = *(const float4*)&Ts[k][tx * 4];
        float sr[4] = {s4.x, s4.y, s4.z, s4.w};
        float qr[4] = {q4.x, q4.y, q4.z, q4.w};
        float tr[4] = {t4.x, t4.y, t4.z, t4.w};
#pragma unroll
        for (int i = 0; i < 4; ++i)
#pragma unroll
            for (int j = 0; j < 4; ++j) {
                aa[i][j] = fmaf(sr[i], qr[j], aa[i][j]);
                bb[i][j] = fmaf(sr[i], tr[j], bb[i][j]);
            }
    }
#pragma unroll
    for (int i = 0; i < 4; ++i) {
        const int crow = c0 + ty * 4 + i;
        const float4 cv = *(const float4*)&c[((size_t)b * CL_ + crow) * H_ + h0 + tx * 4];
        float* ob = out + ((size_t)b * CL_ + crow) * (4 * H_);
        const int hh = h0 + tx * 4;
        float4 av  = make_float4(aa[i][0], aa[i][1], aa[i][2], aa[i][3]);
        float4 bv  = make_float4(bb[i][0], bb[i][1], bb[i][2], bb[i][3]);
        float4 cav = make_float4(cv.x * av.x, cv.y * av.y, cv.z * av.z, cv.w * av.w);
        float4 cbv = make_float4(cv.x * bv.x, cv.y * bv.y, cv.z * bv.z, cv.w * bv.w);
        *(float4*)&ob[hh]           = cv;
        *(float4*)&ob[H_ + hh]      = av;
        *(float4*)&ob[2 * H_ + hh]  = cav;
        *(float4*)&ob[3 * H_ + hh]  = cbv;
    }
}

extern "C" void kernel_launch(void* const* d_in, const int* in_sizes, int n_in,
                              void* d_out, int out_size, void* d_ws, size_t ws_size,
                              hipStream_t stream) {
    const float* c      = (const float*)d_in[0];
    const float* q      = (const float*)d_in[1];
    const int*   c_mask = (const int*)d_in[2];
    const int*   q_mask = (const int*)d_in[3];
    const float* W      = (const float*)d_in[4];
    const float* bias   = (const float*)d_in[5];
    float* out = (float*)d_out;

    // workspace layout (bytes), peak 32.8 MB:
    // [wh 1179648][wl 1179648][qh 1572864][ql 1572864][cph 12582912][cpl 12582912][s 2097152]
    // s1/s2/t alias the cph region (dead after k_gemm_s).
    char* base = (char*)d_ws;
    unsigned short* wh  = (unsigned short*)(base);
    unsigned short* wl  = (unsigned short*)(base + 1179648);
    unsigned short* qh  = (unsigned short*)(base + 2359296);
    unsigned short* ql  = (unsigned short*)(base + 3932160);
    unsigned short* cph = (unsigned short*)(base + 5505024);
    unsigned short* cpl = (unsigned short*)(base + 18087936);
    float* s  = (float*)(base + 30670848);
    float* s1 = (float*)(base + 5505024);            // aliases cph
    float* s2 = (float*)(base + 5505024 + 2097152);
    float* t  = (float*)(base + 5505024 + 4194304);

    dim3 blk(256);
    k_split       <<<dim3(576), blk, 0, stream>>>(W, wh, wl, 147456);   // 589824/4
    k_split       <<<dim3(768), blk, 0, stream>>>(q, qh, ql, 196608);   // 786432/4
    k_gemm_cp     <<<dim3(M_ / 128, H_ / 128), blk, 0, stream>>>(c, wh, wl, bias, cph, cpl);
    k_gemm_s      <<<dim3(M_ / 128),           blk, 0, stream>>>(cph, cpl, qh, ql, s);
    k_softmax_rows<<<dim3(M_ / 4),             blk, 0, stream>>>(s, q_mask, s1);
    k_softmax_cols<<<dim3(B_ * QL_),           blk, 0, stream>>>(s, c_mask, s2);
    k_gemm_t      <<<dim3(H_ / 64, B_),        blk, 0, stream>>>(s2, c, t);
    k_finalize    <<<dim3(H_ / 64, CL_ / 64, B_), blk, 0, stream>>>(s1, q, t, c, out);
}

// Round 3
// 236.918 us; speedup vs baseline: 1.5135x; 1.0877x over previous
//
#include <hip/hip_runtime.h>
#include <math.h>

// BertBidafAttention B=16, CL=512, QL=64, H=768 — restructured:
//   u[b]   = q[b] @ W                  [64,768]  (split-bf16 MFMA, replaces cp: 1.2 GF vs 9.7 GF)
//   beta   = q @ bias                  [1024]
//   s[b]   = c[b] @ u[b]^T + beta      [512,64]  (split-bf16 MFMA)
//   s1     = softmax_q(s)  -> bf16     [8192,64]
//   s2t    = softmax_c(s)^T -> bf16    [b][64][512]
//   tt     = (s2^T @ c)^T -> bf16      [b][768][64]
//   out    = [c, a, c*a, c*bvec],  a = s1@q, bvec = s1@t  (single-bf16 MFMA)

#define B_  16
#define CL_ 512
#define QL_ 64
#define H_  768
#define M_  (B_ * CL_)   // 8192

typedef __attribute__((ext_vector_type(8))) short s8v;   // 8 bf16
typedef __attribute__((ext_vector_type(4))) float f4v;   // MFMA acc

__device__ __forceinline__ unsigned short bf16_rne(float x) {
    unsigned int u = __float_as_uint(x);
    u += 0x7fffu + ((u >> 16) & 1u);
    return (unsigned short)(u >> 16);
}
__device__ __forceinline__ float bf16_f(unsigned short h) {
    return __uint_as_float((unsigned int)h << 16);
}
__device__ __forceinline__ void split2(float x, unsigned short& h, unsigned short& l) {
    h = bf16_rne(x);
    l = bf16_rne(x - bf16_f(h));
}

// ---------- K1: W[d][h] -> wt[h][d] split bf16 (transpose + split) ----------
__global__ __launch_bounds__(256) void k_tw(const float* __restrict__ W,
    unsigned short* __restrict__ wth, unsigned short* __restrict__ wtl)
{
    __shared__ float tile[64][68];
    const int d0 = blockIdx.x * 64, h0 = blockIdx.y * 64;
    const int t = threadIdx.x;
    const int r = t >> 4, c4 = (t & 15) * 4;
#pragma unroll
    for (int i = 0; i < 4; ++i)
        *(float4*)&tile[r + 16 * i][c4] = *(const float4*)&W[(size_t)(d0 + r + 16 * i) * H_ + h0 + c4];
    __syncthreads();
#pragma unroll
    for (int i = 0; i < 4; ++i) {
        int hr = r + 16 * i;
        ushort4 hh, ll;
        split2(tile[c4 + 0][hr], hh.x, ll.x);
        split2(tile[c4 + 1][hr], hh.y, ll.y);
        split2(tile[c4 + 2][hr], hh.z, ll.z);
        split2(tile[c4 + 3][hr], hh.w, ll.w);
        *(ushort4*)&wth[(size_t)(h0 + hr) * H_ + d0 + c4] = hh;
        *(ushort4*)&wtl[(size_t)(h0 + hr) * H_ + d0 + c4] = ll;
    }
}

// ---------- K2: q[b][qr][h] -> qt[b][h][qr] single bf16 ----------
__global__ __launch_bounds__(256) void k_tq(const float* __restrict__ q,
    unsigned short* __restrict__ qt)
{
    __shared__ float tile[64][68];
    const int h0 = blockIdx.x * 64, b = blockIdx.y;
    const int t = threadIdx.x;
    const int r = t >> 4, c4 = (t & 15) * 4;
#pragma unroll
    for (int i = 0; i < 4; ++i)
        *(float4*)&tile[r + 16 * i][c4] = *(const float4*)&q[(size_t)(b * QL_ + r + 16 * i) * H_ + h0 + c4];
    __syncthreads();
#pragma unroll
    for (int i = 0; i < 4; ++i) {
        int hr = r + 16 * i;
        ushort4 hh;
        hh.x = bf16_rne(tile[c4 + 0][hr]);
        hh.y = bf16_rne(tile[c4 + 1][hr]);
        hh.z = bf16_rne(tile[c4 + 2][hr]);
        hh.w = bf16_rne(tile[c4 + 3][hr]);
        *(ushort4*)&qt[((size_t)b * H_ + h0 + hr) * QL_ + c4] = hh;
    }
}

// ---------- K3: u = q @ W (split-bf16, A inline-split, B=wt), out split ----------
__global__ __launch_bounds__(256) void k_u(const float* __restrict__ q,
    const unsigned short* __restrict__ wth, const unsigned short* __restrict__ wtl,
    unsigned short* __restrict__ uh, unsigned short* __restrict__ ul)
{
    const int m0 = blockIdx.x * 64, n0 = blockIdx.y * 64;
    const int t = threadIdx.x, w = t >> 6, lane = t & 63;
    const int fm = lane & 15, quad = lane >> 4;
    const int mrow = m0 + w * 16 + fm;
    f4v acc[4];
#pragma unroll
    for (int j = 0; j < 4; ++j) acc[j] = (f4v){0.f, 0.f, 0.f, 0.f};
    for (int k0 = 0; k0 < H_; k0 += 32) {
        const float* ap = &q[(size_t)mrow * H_ + k0 + quad * 8];
        float4 a0 = *(const float4*)ap, a1 = *(const float4*)(ap + 4);
        float xs[8] = {a0.x, a0.y, a0.z, a0.w, a1.x, a1.y, a1.z, a1.w};
        s8v fah, fal;
#pragma unroll
        for (int j = 0; j < 8; ++j) { unsigned short h, l; split2(xs[j], h, l); fah[j] = (short)h; fal[j] = (short)l; }
#pragma unroll
        for (int tn = 0; tn < 4; ++tn) {
            const size_t bo = (size_t)(n0 + tn * 16 + fm) * H_ + k0 + quad * 8;
            s8v bh = *(const s8v*)&wth[bo];
            s8v bl = *(const s8v*)&wtl[bo];
            acc[tn] = __builtin_amdgcn_mfma_f32_16x16x32_bf16(fah, bh, acc[tn], 0, 0, 0);
            acc[tn] = __builtin_amdgcn_mfma_f32_16x16x32_bf16(fah, bl, acc[tn], 0, 0, 0);
            acc[tn] = __builtin_amdgcn_mfma_f32_16x16x32_bf16(fal, bh, acc[tn], 0, 0, 0);
        }
    }
#pragma unroll
    for (int tn = 0; tn < 4; ++tn) {
        const int col = n0 + tn * 16 + fm;
#pragma unroll
        for (int r = 0; r < 4; ++r) {
            const int row = m0 + w * 16 + quad * 4 + r;
            unsigned short h, l; split2(acc[tn][r], h, l);
            uh[(size_t)row * H_ + col] = h;
            ul[(size_t)row * H_ + col] = l;
        }
    }
}

// ---------- K4: beta[row] = bias . q[row] ----------
__global__ __launch_bounds__(256) void k_beta(const float* __restrict__ q,
    const float* __restrict__ bias, float* __restrict__ beta)
{
    const int row = blockIdx.x * 4 + (threadIdx.x >> 6);
    const int lane = threadIdx.x & 63;
    float p = 0.f;
    for (int d = lane; d < H_; d += 64) p = fmaf(bias[d], q[(size_t)row * H_ + d], p);
#pragma unroll
    for (int o = 32; o; o >>= 1) p += __shfl_xor(p, o);
    if (lane == 0) beta[row] = p;
}

// ---------- K5: s = c @ u^T + beta (split-bf16, A=c inline-split) ----------
__global__ __launch_bounds__(256) void k_s(const float* __restrict__ c,
    const unsigned short* __restrict__ uh, const unsigned short* __restrict__ ul,
    const float* __restrict__ beta, float* __restrict__ s)
{
    const int m0 = blockIdx.x * 32;
    const int batch = m0 >> 9;
    const int t = threadIdx.x, w = t >> 6, lane = t & 63;
    const int fm = lane & 15, quad = lane >> 4;
    const int msub = (w >> 1) * 16, ntile0 = (w & 1) * 2;
    const int mrow = m0 + msub + fm;
    f4v acc[2];
    acc[0] = (f4v){0.f, 0.f, 0.f, 0.f}; acc[1] = acc[0];
    for (int k0 = 0; k0 < H_; k0 += 32) {
        const float* ap = &c[(size_t)mrow * H_ + k0 + quad * 8];
        float4 a0 = *(const float4*)ap, a1 = *(const float4*)(ap + 4);
        float xs[8] = {a0.x, a0.y, a0.z, a0.w, a1.x, a1.y, a1.z, a1.w};
        s8v fah, fal;
#pragma unroll
        for (int j = 0; j < 8; ++j) { unsigned short h, l; split2(xs[j], h, l); fah[j] = (short)h; fal[j] = (short)l; }
#pragma unroll
        for (int i = 0; i < 2; ++i) {
            const int tn = ntile0 + i;
            const size_t bo = (size_t)(batch * QL_ + tn * 16 + fm) * H_ + k0 + quad * 8;
            s8v bh = *(const s8v*)&uh[bo];
            s8v bl = *(const s8v*)&ul[bo];
            acc[i] = __builtin_amdgcn_mfma_f32_16x16x32_bf16(fah, bh, acc[i], 0, 0, 0);
            acc[i] = __builtin_amdgcn_mfma_f32_16x16x32_bf16(fah, bl, acc[i], 0, 0, 0);
            acc[i] = __builtin_amdgcn_mfma_f32_16x16x32_bf16(fal, bh, acc[i], 0, 0, 0);
        }
    }
#pragma unroll
    for (int i = 0; i < 2; ++i) {
        const int col = (ntile0 + i) * 16 + fm;
        const float bb = beta[batch * QL_ + col];
#pragma unroll
        for (int r = 0; r < 4; ++r) {
            const int row = m0 + msub + quad * 4 + r;
            s[(size_t)row * QL_ + col] = acc[i][r] + bb;
        }
    }
}

// ---------- K6: s1 = row softmax (q dim) -> bf16 ----------
__global__ __launch_bounds__(256) void k_sm_rows(const float* __restrict__ s,
    const int* __restrict__ q_mask, unsigned short* __restrict__ s1)
{
    const int row = blockIdx.x * 4 + (threadIdx.x >> 6);
    const int lane = threadIdx.x & 63;
    const int batch = row >> 9;
    float x = q_mask[batch * QL_ + lane] ? s[(size_t)row * QL_ + lane] : -1e30f;
    float mx = x;
#pragma unroll
    for (int o = 32; o; o >>= 1) mx = fmaxf(mx, __shfl_xor(mx, o));
    float e = __expf(x - mx), sm = e;
#pragma unroll
    for (int o = 32; o; o >>= 1) sm += __shfl_xor(sm, o);
    s1[(size_t)row * QL_ + lane] = bf16_rne(e / sm);
}

// ---------- K7: s2^T = col softmax (c dim), transposed -> bf16 [b][q][c] ----------
__global__ __launch_bounds__(256) void k_sm_cols(const float* __restrict__ s,
    const int* __restrict__ c_mask, unsigned short* __restrict__ s2t)
{
    __shared__ float red[4];
    const int b = blockIdx.x >> 6, qi = blockIdx.x & 63;
    const int t = threadIdx.x;
    const float* sb = s + (size_t)b * CL_ * QL_ + qi;
    const int* cm = c_mask + b * CL_;
    float x0 = cm[t] ? sb[(size_t)t * QL_] : -1e30f;
    float x1 = cm[t + 256] ? sb[(size_t)(t + 256) * QL_] : -1e30f;
    float m = fmaxf(x0, x1);
#pragma unroll
    for (int o = 32; o; o >>= 1) m = fmaxf(m, __shfl_xor(m, o));
    if ((t & 63) == 0) red[t >> 6] = m;
    __syncthreads();
    m = fmaxf(fmaxf(red[0], red[1]), fmaxf(red[2], red[3]));
    __syncthreads();
    float e0 = __expf(x0 - m), e1 = __expf(x1 - m);
    float sm = e0 + e1;
#pragma unroll
    for (int o = 32; o; o >>= 1) sm += __shfl_xor(sm, o);
    if ((t & 63) == 0) red[t >> 6] = sm;
    __syncthreads();
    sm = red[0] + red[1] + red[2] + red[3];
    float inv = 1.f / sm;
    unsigned short* o = s2t + ((size_t)b * QL_ + qi) * CL_;
    o[t]       = bf16_rne(e0 * inv);
    o[t + 256] = bf16_rne(e1 * inv);
}

// ---------- K8: tt[b][h][q] = (s2^T @ c)^T (single-bf16 MFMA, c via LDS transpose) ----------
__global__ __launch_bounds__(256) void k_t(const unsigned short* __restrict__ s2t,
    const float* __restrict__ c, unsigned short* __restrict__ tt)
{
    __shared__ unsigned short Bs[64][40];
    const int h0 = blockIdx.x * 64, b = blockIdx.y;
    const int t = threadIdx.x, w = t >> 6, lane = t & 63;
    const int fm = lane & 15, quad = lane >> 4;
    const int dd = t >> 3, hc = (t & 7) * 8;
    f4v acc[4];
#pragma unroll
    for (int j = 0; j < 4; ++j) acc[j] = (f4v){0.f, 0.f, 0.f, 0.f};
    for (int d0 = 0; d0 < CL_; d0 += 32) {
        const float* cp = &c[((size_t)b * CL_ + d0 + dd) * H_ + h0 + hc];
        float4 v0 = *(const float4*)cp, v1 = *(const float4*)(cp + 4);
        float xs[8] = {v0.x, v0.y, v0.z, v0.w, v1.x, v1.y, v1.z, v1.w};
        __syncthreads();
#pragma unroll
        for (int j = 0; j < 8; ++j) Bs[hc + j][dd] = bf16_rne(xs[j]);
        __syncthreads();
        s8v fb = *(const s8v*)&Bs[w * 16 + fm][quad * 8];
#pragma unroll
        for (int tm = 0; tm < 4; ++tm) {
            s8v fa = *(const s8v*)&s2t[((size_t)b * QL_ + tm * 16 + fm) * CL_ + d0 + quad * 8];
            acc[tm] = __builtin_amdgcn_mfma_f32_16x16x32_bf16(fa, fb, acc[tm], 0, 0, 0);
        }
    }
#pragma unroll
    for (int tm = 0; tm < 4; ++tm)
#pragma unroll
        for (int r = 0; r < 4; ++r)
            tt[((size_t)b * H_ + h0 + w * 16 + fm) * QL_ + tm * 16 + quad * 4 + r] = bf16_rne(acc[tm][r]);
}

// ---------- K9: finalize — a = s1@q, bvec = s1@t; out = [c, a, c*a, c*bvec] ----------
__global__ __launch_bounds__(256) void k_fin(const unsigned short* __restrict__ s1,
    const unsigned short* __restrict__ qt, const unsigned short* __restrict__ tt,
    const float* __restrict__ c, float* __restrict__ out)
{
    const int h0 = blockIdx.x * 64;
    const int c0 = blockIdx.y * 256;
    const int b  = blockIdx.z;
    const int t = threadIdx.x, w = t >> 6, lane = t & 63;
    const int fm = lane & 15, quad = lane >> 4;
    const int cbase = c0 + w * 64;
    f4v aa[4][4], bb[4][4];
#pragma unroll
    for (int i = 0; i < 4; ++i)
#pragma unroll
        for (int j = 0; j < 4; ++j) { aa[i][j] = (f4v){0.f, 0.f, 0.f, 0.f}; bb[i][j] = aa[i][j]; }
#pragma unroll
    for (int ks = 0; ks < 2; ++ks) {
        s8v fa[4], fq[4], ft[4];
#pragma unroll
        for (int tm = 0; tm < 4; ++tm)
            fa[tm] = *(const s8v*)&s1[(size_t)(b * CL_ + cbase + tm * 16 + fm) * QL_ + ks * 32 + quad * 8];
#pragma unroll
        for (int tn = 0; tn < 4; ++tn) {
            size_t ro = ((size_t)b * H_ + h0 + tn * 16 + fm) * QL_ + ks * 32 + quad * 8;
            fq[tn] = *(const s8v*)&qt[ro];
            ft[tn] = *(const s8v*)&tt[ro];
        }
#pragma unroll
        for (int tm = 0; tm < 4; ++tm)
#pragma unroll
            for (int tn = 0; tn < 4; ++tn) {
                aa[tm][tn] = __builtin_amdgcn_mfma_f32_16x16x32_bf16(fa[tm], fq[tn], aa[tm][tn], 0, 0, 0);
                bb[tm][tn] = __builtin_amdgcn_mfma_f32_16x16x32_bf16(fa[tm], ft[tn], bb[tm][tn], 0, 0, 0);
            }
    }
#pragma unroll
    for (int tm = 0; tm < 4; ++tm)
#pragma unroll
        for (int tn = 0; tn < 4; ++tn) {
            const int h = h0 + tn * 16 + fm;
#pragma unroll
            for (int r = 0; r < 4; ++r) {
                const int crow = cbase + tm * 16 + quad * 4 + r;
                const float cv = c[((size_t)b * CL_ + crow) * H_ + h];
                const float av = aa[tm][tn][r], bv = bb[tm][tn][r];
                float* ob = out + (size_t)(b * CL_ + crow) * (4 * H_);
                ob[h]           = cv;
                ob[H_ + h]      = av;
                ob[2 * H_ + h]  = cv * av;
                ob[3 * H_ + h]  = cv * bv;
            }
        }
}

extern "C" void kernel_launch(void* const* d_in, const int* in_sizes, int n_in,
                              void* d_out, int out_size, void* d_ws, size_t ws_size,
                              hipStream_t stream) {
    const float* c      = (const float*)d_in[0];
    const float* q      = (const float*)d_in[1];
    const int*   c_mask = (const int*)d_in[2];
    const int*   q_mask = (const int*)d_in[3];
    const float* W      = (const float*)d_in[4];
    const float* bias   = (const float*)d_in[5];
    float* out = (float*)d_out;

    // workspace (bytes, 16B-aligned), total ~12.8 MB
    char* base = (char*)d_ws;
    unsigned short* wth  = (unsigned short*)(base);              // 1179648
    unsigned short* wtl  = (unsigned short*)(base + 1179648);    // 1179648
    unsigned short* qt   = (unsigned short*)(base + 2359296);    // 1572864
    unsigned short* uh   = (unsigned short*)(base + 3932160);    // 1572864
    unsigned short* ul   = (unsigned short*)(base + 5505024);    // 1572864
    float*          beta = (float*)(base + 7077888);             // 4096
    float*          s    = (float*)(base + 7081984);             // 2097152
    unsigned short* s1   = (unsigned short*)(base + 9179136);    // 1048576
    unsigned short* s2t  = (unsigned short*)(base + 10227712);   // 1048576
    unsigned short* tt   = (unsigned short*)(base + 11276288);   // 1572864

    dim3 blk(256);
    k_tw     <<<dim3(12, 12),      blk, 0, stream>>>(W, wth, wtl);
    k_tq     <<<dim3(12, B_),      blk, 0, stream>>>(q, qt);
    k_beta   <<<dim3(256),         blk, 0, stream>>>(q, bias, beta);
    k_u      <<<dim3(16, 12),      blk, 0, stream>>>(q, wth, wtl, uh, ul);
    k_s      <<<dim3(256),         blk, 0, stream>>>(c, uh, ul, beta, s);
    k_sm_rows<<<dim3(M_ / 4),      blk, 0, stream>>>(s, q_mask, s1);
    k_sm_cols<<<dim3(B_ * QL_),    blk, 0, stream>>>(s, c_mask, s2t);
    k_t      <<<dim3(12, B_),      blk, 0, stream>>>(s2t, c, tt);
    k_fin    <<<dim3(12, 2, B_),   blk, 0, stream>>>(s1, qt, tt, c, out);
}